// Round 2
// baseline (2356.284 us; speedup 1.0000x reference)
//
#include <hip/hip_runtime.h>
#include <cstdint>
#include <cstddef>

#define NFEAT 128

// ---------------- degree histogram (int) ----------------

__global__ __launch_bounds__(256) void hist_kernel(const int* __restrict__ src,
                                                   const int* __restrict__ dst,
                                                   int* __restrict__ degs,
                                                   int* __restrict__ degd, int E) {
  int e = blockIdx.x * 256 + threadIdx.x;
  if (e < E) {
    atomicAdd(&degs[src[e]], 1);
    atomicAdd(&degd[dst[e]], 1);
  }
}

// in-place: read int count, write float deg^-1/2 (0 if deg==0)
__global__ __launch_bounds__(256) void invsqrt_kernel(float* __restrict__ a, int n) {
  int i = blockIdx.x * 256 + threadIdx.x;
  if (i < n) {
    int v = reinterpret_cast<int*>(a)[i];
    a[i] = v > 0 ? rsqrtf((float)v) : 0.0f;
  }
}

// ---------------- exclusive scan over degd -> rowptr, cursor ----------------

__global__ __launch_bounds__(256) void scan_kernel(const int* __restrict__ deg,
                                                   int* __restrict__ rowptr,
                                                   int* __restrict__ cursor, int N, int E) {
  __shared__ int tmp[256];
  __shared__ int carry;
  if (threadIdx.x == 0) carry = 0;
  __syncthreads();
  for (int base = 0; base < N; base += 256) {
    int i = base + threadIdx.x;
    int v = (i < N) ? deg[i] : 0;
    tmp[threadIdx.x] = v;
    __syncthreads();
#pragma unroll
    for (int off = 1; off < 256; off <<= 1) {
      int t = (threadIdx.x >= off) ? tmp[threadIdx.x - off] : 0;
      __syncthreads();
      tmp[threadIdx.x] += t;
      __syncthreads();
    }
    int excl = tmp[threadIdx.x] - v;
    if (i < N) {
      int o = carry + excl;
      rowptr[i] = o;
      cursor[i] = o;
    }
    __syncthreads();
    if (threadIdx.x == 255) carry += tmp[255];
    __syncthreads();
  }
  if (threadIdx.x == 0) rowptr[N] = E;
}

// ---------------- scatter edges into CSR buckets ----------------

__global__ __launch_bounds__(256) void bucket_kernel(const int* __restrict__ src,
                                                     const int* __restrict__ dst,
                                                     int* __restrict__ cursor,
                                                     int2* __restrict__ pairs, int E) {
  int e = blockIdx.x * 256 + threadIdx.x;
  if (e < E) {
    int pos = atomicAdd(&cursor[dst[e]], 1);
    pairs[pos] = make_int2(src[e], e);
  }
}

// ---------------- gather aggregation ----------------
// agg[n,f] = sum_{edges e: dst[e]==n} feat[src[e],f]*ns[src[e]]*(mu[e]+sigma[e]*eps[e,f])
// one 32-lane group per node, float4 per lane.

template <bool HAS_A>
__global__ __launch_bounds__(256) void aggregate_kernel(const float* __restrict__ feat,
                                                        const int* __restrict__ rowptr,
                                                        const int2* __restrict__ pairs,
                                                        const float* __restrict__ ns,
                                                        const float* __restrict__ mu,
                                                        const float* __restrict__ sigma,
                                                        const float* __restrict__ eps,
                                                        float* __restrict__ agg, int Nn) {
  int n = blockIdx.x * 8 + (threadIdx.x >> 5);
  if (n >= Nn) return;
  int g = threadIdx.x & 31;
  int beg = rowptr[n];
  int end = rowptr[n + 1];
  float4 acc = make_float4(0.f, 0.f, 0.f, 0.f);
  for (int j = beg; j < end; j++) {
    int2 p = pairs[j];
    int s = p.x;
    float sc = ns[s];
    float4 f = *reinterpret_cast<const float4*>(feat + (size_t)s * NFEAT + g * 4);
    if (HAS_A) {
      int e = p.y;
      float mu_e = mu[e];
      float sg_e = sigma[e];
      float4 ep = *reinterpret_cast<const float4*>(eps + (size_t)e * NFEAT + g * 4);
      acc.x = fmaf(f.x * sc, fmaf(sg_e, ep.x, mu_e), acc.x);
      acc.y = fmaf(f.y * sc, fmaf(sg_e, ep.y, mu_e), acc.y);
      acc.z = fmaf(f.z * sc, fmaf(sg_e, ep.z, mu_e), acc.z);
      acc.w = fmaf(f.w * sc, fmaf(sg_e, ep.w, mu_e), acc.w);
    } else {
      acc.x = fmaf(f.x, sc, acc.x);
      acc.y = fmaf(f.y, sc, acc.y);
      acc.z = fmaf(f.z, sc, acc.z);
      acc.w = fmaf(f.w, sc, acc.w);
    }
  }
  *reinterpret_cast<float4*>(agg + (size_t)n * NFEAT + g * 4) = acc;
}

// ---------------- dense layer: C = relu((A * nd_row) @ W + b) ----------------

template <int NCOL, bool RELU>
__global__ __launch_bounds__(256) void matmul_kernel(const float* __restrict__ A,
                                                     const float* __restrict__ nd,
                                                     const float* __restrict__ W,
                                                     const float* __restrict__ bias,
                                                     float* __restrict__ C, int nrows) {
  constexpr int OCG = NCOL / 4;
  constexpr int RG = 256 / OCG;
  constexpr int ROWS = RG * 4;
  __shared__ float Wl[128 * NCOL];
  for (int i = threadIdx.x; i < 128 * NCOL / 4; i += 256)
    reinterpret_cast<float4*>(Wl)[i] = reinterpret_cast<const float4*>(W)[i];
  __syncthreads();

  const int oc = threadIdx.x % OCG;
  const int rg = threadIdx.x / OCG;
  const int row0 = blockIdx.x * ROWS + rg * 4;

  const float* Arow[4];
#pragma unroll
  for (int i = 0; i < 4; i++) {
    int r = row0 + i;
    Arow[i] = A + (size_t)(r < nrows ? r : 0) * NFEAT;
  }
  float acc[4][4] = {};

#pragma unroll 2
  for (int k = 0; k < 128; k += 4) {
    float4 w0 = *reinterpret_cast<const float4*>(&Wl[(k + 0) * NCOL + oc * 4]);
    float4 w1 = *reinterpret_cast<const float4*>(&Wl[(k + 1) * NCOL + oc * 4]);
    float4 w2 = *reinterpret_cast<const float4*>(&Wl[(k + 2) * NCOL + oc * 4]);
    float4 w3 = *reinterpret_cast<const float4*>(&Wl[(k + 3) * NCOL + oc * 4]);
#pragma unroll
    for (int i = 0; i < 4; i++) {
      float4 a = *reinterpret_cast<const float4*>(Arow[i] + k);
      acc[i][0] = fmaf(a.x, w0.x, acc[i][0]);
      acc[i][1] = fmaf(a.x, w0.y, acc[i][1]);
      acc[i][2] = fmaf(a.x, w0.z, acc[i][2]);
      acc[i][3] = fmaf(a.x, w0.w, acc[i][3]);
      acc[i][0] = fmaf(a.y, w1.x, acc[i][0]);
      acc[i][1] = fmaf(a.y, w1.y, acc[i][1]);
      acc[i][2] = fmaf(a.y, w1.z, acc[i][2]);
      acc[i][3] = fmaf(a.y, w1.w, acc[i][3]);
      acc[i][0] = fmaf(a.z, w2.x, acc[i][0]);
      acc[i][1] = fmaf(a.z, w2.y, acc[i][1]);
      acc[i][2] = fmaf(a.z, w2.z, acc[i][2]);
      acc[i][3] = fmaf(a.z, w2.w, acc[i][3]);
      acc[i][0] = fmaf(a.w, w3.x, acc[i][0]);
      acc[i][1] = fmaf(a.w, w3.y, acc[i][1]);
      acc[i][2] = fmaf(a.w, w3.z, acc[i][2]);
      acc[i][3] = fmaf(a.w, w3.w, acc[i][3]);
    }
  }

  float4 b4 = *reinterpret_cast<const float4*>(bias + oc * 4);
#pragma unroll
  for (int i = 0; i < 4; i++) {
    int r = row0 + i;
    if (r < nrows) {
      float ndv = nd[r];
      float4 o;
      o.x = fmaf(acc[i][0], ndv, b4.x);
      o.y = fmaf(acc[i][1], ndv, b4.y);
      o.z = fmaf(acc[i][2], ndv, b4.z);
      o.w = fmaf(acc[i][3], ndv, b4.w);
      if (RELU) {
        o.x = fmaxf(o.x, 0.0f);
        o.y = fmaxf(o.y, 0.0f);
        o.z = fmaxf(o.z, 0.0f);
        o.w = fmaxf(o.w, 0.0f);
      }
      *reinterpret_cast<float4*>(C + (size_t)r * NCOL + oc * 4) = o;
    }
  }
}

// ---------------- per-edge mu/sigma + NLL accumulation ----------------

template <bool STORE>
__global__ __launch_bounds__(256) void edgedist_kernel(const float* __restrict__ z,
                                                       const int* __restrict__ srcp,
                                                       const int* __restrict__ dstp,
                                                       const float* __restrict__ W_mu,
                                                       const float* __restrict__ b_mu,
                                                       const float* __restrict__ W_ls,
                                                       const float* __restrict__ b_ls,
                                                       float* __restrict__ mu_out,
                                                       float* __restrict__ sigma_out,
                                                       double* __restrict__ nll_acc, int E,
                                                       float vtarget, int acc_idx) {
  __shared__ float wl[512];  // [0:256] W_mu, [256:512] W_ls
  __shared__ float bsum;
  {
    int i = threadIdx.x;
    wl[i] = W_mu[i];
    wl[256 + i] = W_ls[i];
  }
  if (threadIdx.x == 0) bsum = 0.0f;
  __syncthreads();

  int e = blockIdx.x * 8 + (threadIdx.x >> 5);
  int g = threadIdx.x & 31;
  if (e < E) {
    int s = srcp[e];
    int d = dstp[e];
    float4 zs = *reinterpret_cast<const float4*>(z + (size_t)s * NFEAT + g * 4);
    float4 zd = *reinterpret_cast<const float4*>(z + (size_t)d * NFEAT + g * 4);
    zs.x = fmaxf(zs.x, 0.0f); zs.y = fmaxf(zs.y, 0.0f);
    zs.z = fmaxf(zs.z, 0.0f); zs.w = fmaxf(zs.w, 0.0f);
    zd.x = fmaxf(zd.x, 0.0f); zd.y = fmaxf(zd.y, 0.0f);
    zd.z = fmaxf(zd.z, 0.0f); zd.w = fmaxf(zd.w, 0.0f);
    float4 wma = *reinterpret_cast<const float4*>(&wl[g * 4]);
    float4 wmb = *reinterpret_cast<const float4*>(&wl[128 + g * 4]);
    float4 wla = *reinterpret_cast<const float4*>(&wl[256 + g * 4]);
    float4 wlb = *reinterpret_cast<const float4*>(&wl[384 + g * 4]);
    float pm = zs.x * wma.x + zs.y * wma.y + zs.z * wma.z + zs.w * wma.w +
               zd.x * wmb.x + zd.y * wmb.y + zd.z * wmb.z + zd.w * wmb.w;
    float pl = zs.x * wla.x + zs.y * wla.y + zs.z * wla.z + zs.w * wla.w +
               zd.x * wlb.x + zd.y * wlb.y + zd.z * wlb.z + zd.w * wlb.w;
#pragma unroll
    for (int msk = 16; msk >= 1; msk >>= 1) {
      pm += __shfl_xor(pm, msk);
      pl += __shfl_xor(pl, msk);
    }
    if (g == 0) {
      float mu_e = pm + b_mu[0];
      float ls = pl + b_ls[0];
      float sg = expf(ls);
      if (STORE) {
        mu_out[e] = mu_e;
        sigma_out[e] = sg;
      }
      float dv = vtarget - mu_e;
      float lp = -logf(sg) - 0.91893853320467274f - dv * dv / (2.0f * sg * sg);
      atomicAdd(&bsum, lp);
    }
  }
  __syncthreads();
  if (threadIdx.x == 0) unsafeAtomicAdd(&nll_acc[acc_idx], (double)bsum);
}

__global__ void finalize_kernel(const double* __restrict__ nll, float* __restrict__ out,
                                double invE) {
  if (threadIdx.x == 0) out[0] = (float)(-(nll[0] + nll[1]) * invE);
}

// ---------------- host-side orchestration ----------------

extern "C" void kernel_launch(void* const* d_in, const int* in_sizes, int n_in, void* d_out,
                              int out_size, void* d_ws, size_t ws_size, hipStream_t stream) {
  const float* x = (const float*)d_in[0];
  const int* src = (const int*)d_in[1];
  const int* dst = (const int*)d_in[2];
  const int* neg_src = (const int*)d_in[3];
  const int* neg_dst = (const int*)d_in[4];
  const float* eps_first = (const float*)d_in[5];
  const float* eps_rest = (const float*)d_in[6];
  const float* W_mu = (const float*)d_in[7];
  const float* b_mu = (const float*)d_in[8];
  const float* W_ls = (const float*)d_in[9];
  const float* b_ls = (const float*)d_in[10];
  const float* W_enc0 = (const float*)d_in[11];
  const float* b_enc0 = (const float*)d_in[12];
  const float* W_enc1 = (const float*)d_in[13];
  const float* b_enc1 = (const float*)d_in[14];
  const float* W_g0 = (const float*)d_in[15];
  const float* b_g0 = (const float*)d_in[16];
  const float* W_g1 = (const float*)d_in[17];
  const float* b_g1 = (const float*)d_in[18];
  const float* W_g2 = (const float*)d_in[19];
  const float* b_g2 = (const float*)d_in[20];

  const int N = in_sizes[0] / NFEAT;
  const int E = in_sizes[1];
  const int OUTF = 64;

  char* p = (char*)d_ws;
  auto alloc = [&](size_t bytes) -> char* {
    char* r = p;
    p += (bytes + 255) & ~(size_t)255;
    return r;
  };
  double* nll = (double*)alloc(2 * sizeof(double));
  float* ns = (float*)alloc((size_t)N * 4);   // int degree then float ns (in place)
  float* nd = (float*)alloc((size_t)N * 4);
  float* mu = (float*)alloc((size_t)E * 4);
  float* sigma = (float*)alloc((size_t)E * 4);
  int* rowptr = (int*)alloc((size_t)(N + 1) * 4);
  int* cursor = (int*)alloc((size_t)N * 4);
  int2* pairs = (int2*)alloc((size_t)E * 8);
  float* agg = (float*)alloc((size_t)N * NFEAT * 4);
  float* bufH = (float*)alloc((size_t)N * NFEAT * 4);
  float* bufZ = (float*)alloc((size_t)N * NFEAT * 4);

  float* outh = (float*)d_out;  // [N,64] then 1 float nll

  const int eBlocks = (E + 255) / 256;
  const int grpBlocks = (E + 7) / 8;
  const int aggBlocks = (N + 7) / 8;
  const int mmBlocks128 = (N + 31) / 32;
  const int mmBlocks64 = (N + 63) / 64;
  const int nBlocks = (N + 255) / 256;

  hipMemsetAsync(nll, 0, 2 * sizeof(double), stream);
  hipMemsetAsync(ns, 0, (size_t)N * 4, stream);
  hipMemsetAsync(nd, 0, (size_t)N * 4, stream);

  // CSR build (dst buckets) + degree normalization
  hist_kernel<<<eBlocks, 256, 0, stream>>>(src, dst, (int*)ns, (int*)nd, E);
  scan_kernel<<<1, 256, 0, stream>>>((const int*)nd, rowptr, cursor, N, E);
  invsqrt_kernel<<<nBlocks, 256, 0, stream>>>(ns, N);
  invsqrt_kernel<<<nBlocks, 256, 0, stream>>>(nd, N);
  bucket_kernel<<<eBlocks, 256, 0, stream>>>(src, dst, cursor, pairs, E);

  // encoder layer 0
  aggregate_kernel<false><<<aggBlocks, 256, 0, stream>>>(x, rowptr, pairs, ns, nullptr,
                                                         nullptr, nullptr, agg, N);
  matmul_kernel<128, true><<<mmBlocks128, 256, 0, stream>>>(agg, nd, W_enc0, b_enc0, bufH, N);

  // encoder layer 1 -> z
  aggregate_kernel<false><<<aggBlocks, 256, 0, stream>>>(bufH, rowptr, pairs, ns, nullptr,
                                                         nullptr, nullptr, agg, N);
  matmul_kernel<128, true><<<mmBlocks128, 256, 0, stream>>>(agg, nd, W_enc1, b_enc1, bufZ, N);

  // edge posterior (positive edges, store mu/sigma, nll vs v=1)
  edgedist_kernel<true><<<grpBlocks, 256, 0, stream>>>(bufZ, src, dst, W_mu, b_mu, W_ls, b_ls,
                                                       mu, sigma, nll, E, 1.0f, 0);
  // negative edges, nll vs v=0
  edgedist_kernel<false><<<grpBlocks, 256, 0, stream>>>(bufZ, neg_src, neg_dst, W_mu, b_mu,
                                                        W_ls, b_ls, nullptr, nullptr, nll, E,
                                                        0.0f, 1);

  // stochastic layer 0
  aggregate_kernel<true><<<aggBlocks, 256, 0, stream>>>(x, rowptr, pairs, ns, mu, sigma,
                                                        eps_first, agg, N);
  matmul_kernel<128, true><<<mmBlocks128, 256, 0, stream>>>(agg, nd, W_g0, b_g0, bufH, N);

  // stochastic layer 1
  aggregate_kernel<true><<<aggBlocks, 256, 0, stream>>>(bufH, rowptr, pairs, ns, mu, sigma,
                                                        eps_rest, agg, N);
  matmul_kernel<128, true><<<mmBlocks128, 256, 0, stream>>>(agg, nd, W_g1, b_g1, bufZ, N);

  // stochastic layer 2 (output, no relu)
  aggregate_kernel<true><<<aggBlocks, 256, 0, stream>>>(bufZ, rowptr, pairs, ns, mu, sigma,
                                                        eps_rest, agg, N);
  matmul_kernel<64, false><<<mmBlocks64, 256, 0, stream>>>(agg, nd, W_g2, b_g2, outh, N);

  // nll_reg scalar
  finalize_kernel<<<1, 64, 0, stream>>>(nll, outh + (size_t)N * OUTF, 1.0 / (double)E);
}

// Round 7
// 930.893 us; speedup vs baseline: 2.5312x; 2.5312x over previous
//
#include <hip/hip_runtime.h>
#include <cstdint>
#include <cstddef>

#define NFEAT 128
#define EBLK 1024  // blocks for edge kernel / size of partial array

typedef float f32x4 __attribute__((ext_vector_type(4)));

__device__ __forceinline__ float4 nt_load4(const float4* p) {
  f32x4 t = __builtin_nontemporal_load(reinterpret_cast<const f32x4*>(p));
  return make_float4(t.x, t.y, t.z, t.w);
}

// ---------------- degree histogram (int) ----------------

__global__ __launch_bounds__(256) void hist_kernel(const int* __restrict__ src,
                                                   const int* __restrict__ dst,
                                                   int* __restrict__ degs,
                                                   int* __restrict__ degd, int E) {
  int e = blockIdx.x * 256 + threadIdx.x;
  if (e < E) {
    atomicAdd(&degs[src[e]], 1);
    atomicAdd(&degd[dst[e]], 1);
  }
}

// in-place: read int count, write float deg^-1/2 (0 if deg==0)
__global__ __launch_bounds__(256) void invsqrt_kernel(float* __restrict__ a, int n) {
  int i = blockIdx.x * 256 + threadIdx.x;
  if (i < n) {
    int v = reinterpret_cast<int*>(a)[i];
    a[i] = v > 0 ? rsqrtf((float)v) : 0.0f;
  }
}

// ---------------- 3-phase exclusive scan (deg -> rowptr/cursor) ----------------
// chunk = 1024 elements per block (256 threads x 4)

__global__ __launch_bounds__(256) void scan_partial(const int* __restrict__ deg,
                                                    int* __restrict__ bsum, int N) {
  __shared__ int tmp[256];
  int t = threadIdx.x, b = blockIdx.x;
  int i0 = b * 1024 + t * 4;
  int s = 0;
#pragma unroll
  for (int k = 0; k < 4; k++) {
    int i = i0 + k;
    if (i < N) s += deg[i];
  }
  tmp[t] = s;
  __syncthreads();
  for (int off = 1; off < 256; off <<= 1) {
    int v = (t >= off) ? tmp[t - off] : 0;
    __syncthreads();
    tmp[t] += v;
    __syncthreads();
  }
  if (t == 255) bsum[b] = tmp[255];
}

__global__ __launch_bounds__(256) void scan_mid(int* __restrict__ bsum, int nb) {
  __shared__ int tmp[256];
  int t = threadIdx.x;
  int v = (t < nb) ? bsum[t] : 0;
  tmp[t] = v;
  __syncthreads();
  for (int off = 1; off < 256; off <<= 1) {
    int u = (t >= off) ? tmp[t - off] : 0;
    __syncthreads();
    tmp[t] += u;
    __syncthreads();
  }
  if (t < nb) bsum[t] = tmp[t] - v;  // exclusive
}

__global__ __launch_bounds__(256) void scan_final(const int* __restrict__ deg,
                                                  const int* __restrict__ bsum,
                                                  int* __restrict__ rowptr,
                                                  int* __restrict__ cursor, int N, int E) {
  __shared__ int tmp[256];
  int t = threadIdx.x, b = blockIdx.x;
  int i0 = b * 1024 + t * 4;
  int v[4];
  int s = 0;
#pragma unroll
  for (int k = 0; k < 4; k++) {
    int i = i0 + k;
    v[k] = (i < N) ? deg[i] : 0;
    s += v[k];
  }
  tmp[t] = s;
  __syncthreads();
  for (int off = 1; off < 256; off <<= 1) {
    int u = (t >= off) ? tmp[t - off] : 0;
    __syncthreads();
    tmp[t] += u;
    __syncthreads();
  }
  int base = bsum[b] + (tmp[t] - s);
#pragma unroll
  for (int k = 0; k < 4; k++) {
    int i = i0 + k;
    if (i < N) {
      rowptr[i] = base;
      cursor[i] = base;
      base += v[k];
    }
  }
  if (b == 0 && t == 0) rowptr[N] = E;
}

// ---------------- scatter edges into CSR buckets ----------------

__global__ __launch_bounds__(256) void bucket_kernel(const int* __restrict__ src,
                                                     const int* __restrict__ dst,
                                                     int* __restrict__ cursor,
                                                     int2* __restrict__ pairs, int E) {
  int e = blockIdx.x * 256 + threadIdx.x;
  if (e < E) {
    int pos = atomicAdd(&cursor[dst[e]], 1);
    pairs[pos] = make_int2(src[e], e);
  }
}

// ---------------- prescale: xs = x * ns[row] ----------------

__global__ __launch_bounds__(256) void prescale_kernel(const float* __restrict__ x,
                                                       const float* __restrict__ ns,
                                                       float* __restrict__ xs, int Nn) {
  int i = blockIdx.x * 256 + threadIdx.x;  // one float4 per thread
  int total = Nn * (NFEAT / 4);
  if (i < total) {
    int row = i >> 5;
    float s = ns[row];
    float4 v = reinterpret_cast<const float4*>(x)[i];
    v.x *= s; v.y *= s; v.z *= s; v.w *= s;
    reinterpret_cast<float4*>(xs)[i] = v;
  }
}

// ---------------- gather aggregation ----------------
// agg[n,f] = sum_{e: dst[e]==n} feat[src[e],f] * [ns[src[e]] if SCALE_SRC]
//                                               * (mu[e] + sigma[e]*eps[e,f] if HAS_A)
// one 32-lane group per node, float4 per lane; 2-edge unroll for MLP.

template <bool HAS_A, bool NT, bool SCALE_SRC>
__global__ __launch_bounds__(256) void aggregate_kernel(const float* __restrict__ feat,
                                                        const int* __restrict__ rowptr,
                                                        const int2* __restrict__ pairs,
                                                        const float* __restrict__ ns,
                                                        const float2* __restrict__ musig,
                                                        const float* __restrict__ eps,
                                                        float* __restrict__ agg, int Nn) {
  int n = blockIdx.x * 8 + (threadIdx.x >> 5);
  if (n >= Nn) return;
  int g = threadIdx.x & 31;
  int beg = rowptr[n];
  int end = rowptr[n + 1];
  float4 acc = make_float4(0.f, 0.f, 0.f, 0.f);
  int j = beg;
  for (; j + 1 < end; j += 2) {
    int2 p0 = pairs[j];
    int2 p1 = pairs[j + 1];
    float4 f0 = *(reinterpret_cast<const float4*>(feat + (size_t)p0.x * NFEAT) + g);
    float4 f1 = *(reinterpret_cast<const float4*>(feat + (size_t)p1.x * NFEAT) + g);
    if (SCALE_SRC) {
      float s0 = ns[p0.x];
      float s1 = ns[p1.x];
      f0.x *= s0; f0.y *= s0; f0.z *= s0; f0.w *= s0;
      f1.x *= s1; f1.y *= s1; f1.z *= s1; f1.w *= s1;
    }
    if (HAS_A) {
      float2 ms0 = musig[p0.y];
      float2 ms1 = musig[p1.y];
      const float4* e0p = reinterpret_cast<const float4*>(eps + (size_t)p0.y * NFEAT) + g;
      const float4* e1p = reinterpret_cast<const float4*>(eps + (size_t)p1.y * NFEAT) + g;
      float4 e0 = NT ? nt_load4(e0p) : *e0p;
      float4 e1 = NT ? nt_load4(e1p) : *e1p;
      acc.x = fmaf(f0.x, fmaf(ms0.y, e0.x, ms0.x), acc.x);
      acc.y = fmaf(f0.y, fmaf(ms0.y, e0.y, ms0.x), acc.y);
      acc.z = fmaf(f0.z, fmaf(ms0.y, e0.z, ms0.x), acc.z);
      acc.w = fmaf(f0.w, fmaf(ms0.y, e0.w, ms0.x), acc.w);
      acc.x = fmaf(f1.x, fmaf(ms1.y, e1.x, ms1.x), acc.x);
      acc.y = fmaf(f1.y, fmaf(ms1.y, e1.y, ms1.x), acc.y);
      acc.z = fmaf(f1.z, fmaf(ms1.y, e1.z, ms1.x), acc.z);
      acc.w = fmaf(f1.w, fmaf(ms1.y, e1.w, ms1.x), acc.w);
    } else {
      acc.x += f0.x + f1.x;
      acc.y += f0.y + f1.y;
      acc.z += f0.z + f1.z;
      acc.w += f0.w + f1.w;
    }
  }
  if (j < end) {
    int2 p0 = pairs[j];
    float4 f0 = *(reinterpret_cast<const float4*>(feat + (size_t)p0.x * NFEAT) + g);
    if (SCALE_SRC) {
      float s0 = ns[p0.x];
      f0.x *= s0; f0.y *= s0; f0.z *= s0; f0.w *= s0;
    }
    if (HAS_A) {
      float2 ms0 = musig[p0.y];
      const float4* e0p = reinterpret_cast<const float4*>(eps + (size_t)p0.y * NFEAT) + g;
      float4 e0 = NT ? nt_load4(e0p) : *e0p;
      acc.x = fmaf(f0.x, fmaf(ms0.y, e0.x, ms0.x), acc.x);
      acc.y = fmaf(f0.y, fmaf(ms0.y, e0.y, ms0.x), acc.y);
      acc.z = fmaf(f0.z, fmaf(ms0.y, e0.z, ms0.x), acc.z);
      acc.w = fmaf(f0.w, fmaf(ms0.y, e0.w, ms0.x), acc.w);
    } else {
      acc.x += f0.x; acc.y += f0.y; acc.z += f0.z; acc.w += f0.w;
    }
  }
  *reinterpret_cast<float4*>(agg + (size_t)n * NFEAT + g * 4) = acc;
}

// ---------------- dense layer: C = [ns_r *] relu((A*nd_r) @ W + b) ----------------

template <int NCOL, bool RELU, bool SCALE_NS>
__global__ __launch_bounds__(256) void matmul_kernel(const float* __restrict__ A,
                                                     const float* __restrict__ nd,
                                                     const float* __restrict__ ns,
                                                     const float* __restrict__ W,
                                                     const float* __restrict__ bias,
                                                     float* __restrict__ C, int nrows) {
  constexpr int OCG = NCOL / 4;
  constexpr int RG = 256 / OCG;
  constexpr int ROWS = RG * 4;
  __shared__ float Wl[128 * NCOL];
  for (int i = threadIdx.x; i < 128 * NCOL / 4; i += 256)
    reinterpret_cast<float4*>(Wl)[i] = reinterpret_cast<const float4*>(W)[i];
  __syncthreads();

  const int oc = threadIdx.x % OCG;
  const int rg = threadIdx.x / OCG;
  const int row0 = blockIdx.x * ROWS + rg * 4;

  const float* Arow[4];
#pragma unroll
  for (int i = 0; i < 4; i++) {
    int r = row0 + i;
    Arow[i] = A + (size_t)(r < nrows ? r : 0) * NFEAT;
  }
  float acc[4][4] = {};

#pragma unroll 2
  for (int k = 0; k < 128; k += 4) {
    float4 w0 = *reinterpret_cast<const float4*>(&Wl[(k + 0) * NCOL + oc * 4]);
    float4 w1 = *reinterpret_cast<const float4*>(&Wl[(k + 1) * NCOL + oc * 4]);
    float4 w2 = *reinterpret_cast<const float4*>(&Wl[(k + 2) * NCOL + oc * 4]);
    float4 w3 = *reinterpret_cast<const float4*>(&Wl[(k + 3) * NCOL + oc * 4]);
#pragma unroll
    for (int i = 0; i < 4; i++) {
      float4 a = *reinterpret_cast<const float4*>(Arow[i] + k);
      acc[i][0] = fmaf(a.x, w0.x, acc[i][0]);
      acc[i][1] = fmaf(a.x, w0.y, acc[i][1]);
      acc[i][2] = fmaf(a.x, w0.z, acc[i][2]);
      acc[i][3] = fmaf(a.x, w0.w, acc[i][3]);
      acc[i][0] = fmaf(a.y, w1.x, acc[i][0]);
      acc[i][1] = fmaf(a.y, w1.y, acc[i][1]);
      acc[i][2] = fmaf(a.y, w1.z, acc[i][2]);
      acc[i][3] = fmaf(a.y, w1.w, acc[i][3]);
      acc[i][0] = fmaf(a.z, w2.x, acc[i][0]);
      acc[i][1] = fmaf(a.z, w2.y, acc[i][1]);
      acc[i][2] = fmaf(a.z, w2.z, acc[i][2]);
      acc[i][3] = fmaf(a.z, w2.w, acc[i][3]);
      acc[i][0] = fmaf(a.w, w3.x, acc[i][0]);
      acc[i][1] = fmaf(a.w, w3.y, acc[i][1]);
      acc[i][2] = fmaf(a.w, w3.z, acc[i][2]);
      acc[i][3] = fmaf(a.w, w3.w, acc[i][3]);
    }
  }

  float4 b4 = *reinterpret_cast<const float4*>(bias + oc * 4);
#pragma unroll
  for (int i = 0; i < 4; i++) {
    int r = row0 + i;
    if (r < nrows) {
      float ndv = nd[r];
      float4 o;
      o.x = fmaf(acc[i][0], ndv, b4.x);
      o.y = fmaf(acc[i][1], ndv, b4.y);
      o.z = fmaf(acc[i][2], ndv, b4.z);
      o.w = fmaf(acc[i][3], ndv, b4.w);
      if (RELU) {
        o.x = fmaxf(o.x, 0.0f);
        o.y = fmaxf(o.y, 0.0f);
        o.z = fmaxf(o.z, 0.0f);
        o.w = fmaxf(o.w, 0.0f);
      }
      if (SCALE_NS) {
        float nsv = ns[r];
        o.x *= nsv; o.y *= nsv; o.z *= nsv; o.w *= nsv;
      }
      *reinterpret_cast<float4*>(C + (size_t)r * NCOL + oc * 4) = o;
    }
  }
}

// ---------------- per-node edge-MLP terms ----------------
// nt[n] = (dot(relu(z[n]),Wmu[0:128]), dot(relu(z[n]),Wmu[128:256]),
//          dot(relu(z[n]),Wls[0:128]), dot(relu(z[n]),Wls[128:256]))

__global__ __launch_bounds__(256) void node_terms_kernel(const float* __restrict__ z,
                                                         const float* __restrict__ W_mu,
                                                         const float* __restrict__ W_ls,
                                                         float4* __restrict__ nt, int Nn) {
  __shared__ float wl[512];
  {
    int i = threadIdx.x;
    wl[i] = W_mu[i];
    wl[256 + i] = W_ls[i];
  }
  __syncthreads();
  int n = blockIdx.x * 8 + (threadIdx.x >> 5);
  if (n >= Nn) return;
  int g = threadIdx.x & 31;
  float4 zv = *reinterpret_cast<const float4*>(z + (size_t)n * NFEAT + g * 4);
  zv.x = fmaxf(zv.x, 0.f); zv.y = fmaxf(zv.y, 0.f);
  zv.z = fmaxf(zv.z, 0.f); zv.w = fmaxf(zv.w, 0.f);
  float4 wma = *reinterpret_cast<const float4*>(&wl[g * 4]);
  float4 wmb = *reinterpret_cast<const float4*>(&wl[128 + g * 4]);
  float4 wla = *reinterpret_cast<const float4*>(&wl[256 + g * 4]);
  float4 wlb = *reinterpret_cast<const float4*>(&wl[384 + g * 4]);
  float pma = zv.x * wma.x + zv.y * wma.y + zv.z * wma.z + zv.w * wma.w;
  float pmb = zv.x * wmb.x + zv.y * wmb.y + zv.z * wmb.z + zv.w * wmb.w;
  float pla = zv.x * wla.x + zv.y * wla.y + zv.z * wla.z + zv.w * wla.w;
  float plb = zv.x * wlb.x + zv.y * wlb.y + zv.z * wlb.z + zv.w * wlb.w;
#pragma unroll
  for (int m = 16; m >= 1; m >>= 1) {
    pma += __shfl_xor(pma, m);
    pmb += __shfl_xor(pmb, m);
    pla += __shfl_xor(pla, m);
    plb += __shfl_xor(plb, m);
  }
  if (g == 0) nt[n] = make_float4(pma, pmb, pla, plb);
}

// ---------------- per-edge mu/sigma + NLL partials ----------------
// idx < E: positive edge (store musig, target 1); idx >= E: negative (target 0)

__global__ __launch_bounds__(256) void edge_kernel(const float4* __restrict__ nt,
                                                   const int* __restrict__ src,
                                                   const int* __restrict__ dst,
                                                   const int* __restrict__ neg_src,
                                                   const int* __restrict__ neg_dst,
                                                   const float* __restrict__ b_mu,
                                                   const float* __restrict__ b_ls,
                                                   float2* __restrict__ musig,
                                                   double2* __restrict__ partial, int E) {
  const float bmu = b_mu[0];
  const float bls = b_ls[0];
  double accP = 0.0, accN = 0.0;
  int stride = gridDim.x * 256;
  for (int idx = blockIdx.x * 256 + threadIdx.x; idx < 2 * E; idx += stride) {
    bool pos = idx < E;
    int e = pos ? idx : idx - E;
    int s = pos ? src[e] : neg_src[e];
    int d = pos ? dst[e] : neg_dst[e];
    float4 a = nt[s];
    float4 b = nt[d];
    float mu = a.x + b.y + bmu;
    float ls = a.z + b.w + bls;
    float sg = expf(ls);
    if (pos) musig[e] = make_float2(mu, sg);
    float dv = (pos ? 1.0f : 0.0f) - mu;
    float lp = -ls - 0.91893853320467274f - dv * dv / (2.0f * sg * sg);
    if (pos) accP += (double)lp; else accN += (double)lp;
  }
#pragma unroll
  for (int m = 1; m < 64; m <<= 1) {
    accP += __shfl_xor(accP, m);
    accN += __shfl_xor(accN, m);
  }
  __shared__ double2 wsum[4];
  if ((threadIdx.x & 63) == 0) wsum[threadIdx.x >> 6] = make_double2(accP, accN);
  __syncthreads();
  if (threadIdx.x == 0) {
    double sp = wsum[0].x + wsum[1].x + wsum[2].x + wsum[3].x;
    double sn = wsum[0].y + wsum[1].y + wsum[2].y + wsum[3].y;
    partial[blockIdx.x] = make_double2(sp, sn);
  }
}

__global__ __launch_bounds__(256) void finalize_kernel(const double2* __restrict__ partial,
                                                       int nb, float* __restrict__ out,
                                                       double invE) {
  double sp = 0.0, sn = 0.0;
  for (int i = threadIdx.x; i < nb; i += 256) {
    double2 pv = partial[i];
    sp += pv.x;
    sn += pv.y;
  }
#pragma unroll
  for (int m = 1; m < 64; m <<= 1) {
    sp += __shfl_xor(sp, m);
    sn += __shfl_xor(sn, m);
  }
  __shared__ double2 wsum[4];
  if ((threadIdx.x & 63) == 0) wsum[threadIdx.x >> 6] = make_double2(sp, sn);
  __syncthreads();
  if (threadIdx.x == 0) {
    double SP = wsum[0].x + wsum[1].x + wsum[2].x + wsum[3].x;
    double SN = wsum[0].y + wsum[1].y + wsum[2].y + wsum[3].y;
    out[0] = (float)(-(SP + SN) * invE);
  }
}

// ---------------- host-side orchestration ----------------

extern "C" void kernel_launch(void* const* d_in, const int* in_sizes, int n_in, void* d_out,
                              int out_size, void* d_ws, size_t ws_size, hipStream_t stream) {
  const float* x = (const float*)d_in[0];
  const int* src = (const int*)d_in[1];
  const int* dst = (const int*)d_in[2];
  const int* neg_src = (const int*)d_in[3];
  const int* neg_dst = (const int*)d_in[4];
  const float* eps_first = (const float*)d_in[5];
  const float* eps_rest = (const float*)d_in[6];
  const float* W_mu = (const float*)d_in[7];
  const float* b_mu = (const float*)d_in[8];
  const float* W_ls = (const float*)d_in[9];
  const float* b_ls = (const float*)d_in[10];
  const float* W_enc0 = (const float*)d_in[11];
  const float* b_enc0 = (const float*)d_in[12];
  const float* W_enc1 = (const float*)d_in[13];
  const float* b_enc1 = (const float*)d_in[14];
  const float* W_g0 = (const float*)d_in[15];
  const float* b_g0 = (const float*)d_in[16];
  const float* W_g1 = (const float*)d_in[17];
  const float* b_g1 = (const float*)d_in[18];
  const float* W_g2 = (const float*)d_in[19];
  const float* b_g2 = (const float*)d_in[20];

  const int N = in_sizes[0] / NFEAT;
  const int E = in_sizes[1];
  const int OUTF = 64;

  auto rnd = [](size_t b) { return (b + 255) & ~(size_t)255; };
  // fixed allocations (everything except xs):
  const size_t fixedBytes = rnd(EBLK * sizeof(double2)) + rnd((size_t)N * 4) * 2 +
                            rnd((size_t)E * 8) + rnd((size_t)(N + 1) * 4) +
                            rnd((size_t)N * 4) + rnd(256 * 4) + rnd((size_t)E * 8) +
                            rnd((size_t)N * 16) + 3 * rnd((size_t)N * NFEAT * 4);
  const bool useXs = fixedBytes + rnd((size_t)N * NFEAT * 4) <= ws_size;

  char* p = (char*)d_ws;
  auto alloc = [&](size_t bytes) -> char* {
    char* r = p;
    p += (bytes + 255) & ~(size_t)255;
    return r;
  };
  double2* partial = (double2*)alloc(EBLK * sizeof(double2));
  float* ns = (float*)alloc((size_t)N * 4);   // int degree then float ns, in place
  float* nd = (float*)alloc((size_t)N * 4);
  float2* musig = (float2*)alloc((size_t)E * 8);
  int* rowptr = (int*)alloc((size_t)(N + 1) * 4);
  int* cursor = (int*)alloc((size_t)N * 4);
  int* bsum = (int*)alloc(256 * 4);
  int2* pairs = (int2*)alloc((size_t)E * 8);
  float4* nt = (float4*)alloc((size_t)N * 16);
  float* agg = (float*)alloc((size_t)N * NFEAT * 4);
  float* bufH = (float*)alloc((size_t)N * NFEAT * 4);
  float* bufZ = (float*)alloc((size_t)N * NFEAT * 4);
  float* xs = useXs ? (float*)alloc((size_t)N * NFEAT * 4) : nullptr;

  float* outh = (float*)d_out;  // [N,64] then 1 float nll

  const int eBlocks = (E + 255) / 256;
  const int aggBlocks = (N + 7) / 8;
  const int mmBlocks128 = (N + 31) / 32;
  const int mmBlocks64 = (N + 63) / 64;
  const int nChunks = (N + 1023) / 1024;  // must be <= 256 (N=50k -> 49)

  (void)hipMemsetAsync(ns, 0, (size_t)N * 4, stream);
  (void)hipMemsetAsync(nd, 0, (size_t)N * 4, stream);

  // CSR build (dst buckets) + degree normalization
  hist_kernel<<<eBlocks, 256, 0, stream>>>(src, dst, (int*)ns, (int*)nd, E);
  scan_partial<<<nChunks, 256, 0, stream>>>((const int*)nd, bsum, N);
  scan_mid<<<1, 256, 0, stream>>>(bsum, nChunks);
  scan_final<<<nChunks, 256, 0, stream>>>((const int*)nd, bsum, rowptr, cursor, N, E);
  invsqrt_kernel<<<(N + 255) / 256, 256, 0, stream>>>(ns, N);
  invsqrt_kernel<<<(N + 255) / 256, 256, 0, stream>>>(nd, N);
  bucket_kernel<<<eBlocks, 256, 0, stream>>>(src, dst, cursor, pairs, E);

  const float* x0 = x;  // feat source for x-consuming aggregates
  if (useXs) {
    prescale_kernel<<<(N * 32 + 255) / 256, 256, 0, stream>>>(x, ns, xs, N);
    x0 = xs;
  }

  // encoder layer 0: bufH = ns * relu((agg(x*ns)*nd) @ W_enc0 + b)
  if (useXs)
    aggregate_kernel<false, false, false><<<aggBlocks, 256, 0, stream>>>(
        x0, rowptr, pairs, ns, nullptr, nullptr, agg, N);
  else
    aggregate_kernel<false, false, true><<<aggBlocks, 256, 0, stream>>>(
        x0, rowptr, pairs, ns, nullptr, nullptr, agg, N);
  matmul_kernel<128, true, true><<<mmBlocks128, 256, 0, stream>>>(agg, nd, ns, W_enc0,
                                                                  b_enc0, bufH, N);

  // encoder layer 1: bufZ = z (unscaled)
  aggregate_kernel<false, false, false><<<aggBlocks, 256, 0, stream>>>(
      bufH, rowptr, pairs, ns, nullptr, nullptr, agg, N);
  matmul_kernel<128, true, false><<<mmBlocks128, 256, 0, stream>>>(agg, nd, ns, W_enc1,
                                                                   b_enc1, bufZ, N);

  // per-node edge-MLP terms, then per-edge mu/sigma + nll partials
  node_terms_kernel<<<aggBlocks, 256, 0, stream>>>(bufZ, W_mu, W_ls, nt, N);
  edge_kernel<<<EBLK, 256, 0, stream>>>(nt, src, dst, neg_src, neg_dst, b_mu, b_ls, musig,
                                        partial, E);

  // stochastic layer 0 (eps_first, single-use -> nontemporal)
  if (useXs)
    aggregate_kernel<true, true, false><<<aggBlocks, 256, 0, stream>>>(
        x0, rowptr, pairs, ns, musig, eps_first, agg, N);
  else
    aggregate_kernel<true, true, true><<<aggBlocks, 256, 0, stream>>>(
        x0, rowptr, pairs, ns, musig, eps_first, agg, N);
  matmul_kernel<128, true, true><<<mmBlocks128, 256, 0, stream>>>(agg, nd, ns, W_g0, b_g0,
                                                                  bufH, N);

  // stochastic layer 1 (eps_rest, reused -> cached)
  aggregate_kernel<true, false, false><<<aggBlocks, 256, 0, stream>>>(
      bufH, rowptr, pairs, ns, musig, eps_rest, agg, N);
  matmul_kernel<128, true, true><<<mmBlocks128, 256, 0, stream>>>(agg, nd, ns, W_g1, b_g1,
                                                                  bufZ, N);

  // stochastic layer 2 (output, no relu, no scale)
  aggregate_kernel<true, false, false><<<aggBlocks, 256, 0, stream>>>(
      bufZ, rowptr, pairs, ns, musig, eps_rest, agg, N);
  matmul_kernel<64, false, false><<<mmBlocks64, 256, 0, stream>>>(agg, nd, ns, W_g2, b_g2,
                                                                  outh, N);

  // nll_reg scalar
  finalize_kernel<<<1, 256, 0, stream>>>(partial, EBLK, outh + (size_t)N * OUTF,
                                         1.0 / (double)E);
}

// Round 8
// 925.626 us; speedup vs baseline: 2.5456x; 1.0057x over previous
//
#include <hip/hip_runtime.h>
#include <cstdint>
#include <cstddef>

#define NFEAT 128
#define EBLK 1024  // blocks for edge kernel / size of partial array

typedef float f32x4 __attribute__((ext_vector_type(4)));

__device__ __forceinline__ float4 nt_load4(const float4* p) {
  f32x4 t = __builtin_nontemporal_load(reinterpret_cast<const f32x4*>(p));
  return make_float4(t.x, t.y, t.z, t.w);
}

// ---------------- degree histogram (int) ----------------

__global__ __launch_bounds__(256) void hist_kernel(const int* __restrict__ src,
                                                   const int* __restrict__ dst,
                                                   int* __restrict__ degs,
                                                   int* __restrict__ degd, int E) {
  int e = blockIdx.x * 256 + threadIdx.x;
  if (e < E) {
    atomicAdd(&degs[src[e]], 1);
    atomicAdd(&degd[dst[e]], 1);
  }
}

// in-place: read int count, write float deg^-1/2 (0 if deg==0)
__global__ __launch_bounds__(256) void invsqrt_kernel(float* __restrict__ a, int n) {
  int i = blockIdx.x * 256 + threadIdx.x;
  if (i < n) {
    int v = reinterpret_cast<int*>(a)[i];
    a[i] = v > 0 ? rsqrtf((float)v) : 0.0f;
  }
}

// ---------------- 3-phase exclusive scan (deg -> rowptr/cursor) ----------------
// chunk = 1024 elements per block (256 threads x 4)

__global__ __launch_bounds__(256) void scan_partial(const int* __restrict__ deg,
                                                    int* __restrict__ bsum, int N) {
  __shared__ int tmp[256];
  int t = threadIdx.x, b = blockIdx.x;
  int i0 = b * 1024 + t * 4;
  int s = 0;
#pragma unroll
  for (int k = 0; k < 4; k++) {
    int i = i0 + k;
    if (i < N) s += deg[i];
  }
  tmp[t] = s;
  __syncthreads();
  for (int off = 1; off < 256; off <<= 1) {
    int v = (t >= off) ? tmp[t - off] : 0;
    __syncthreads();
    tmp[t] += v;
    __syncthreads();
  }
  if (t == 255) bsum[b] = tmp[255];
}

__global__ __launch_bounds__(256) void scan_mid(int* __restrict__ bsum, int nb) {
  __shared__ int tmp[256];
  int t = threadIdx.x;
  int v = (t < nb) ? bsum[t] : 0;
  tmp[t] = v;
  __syncthreads();
  for (int off = 1; off < 256; off <<= 1) {
    int u = (t >= off) ? tmp[t - off] : 0;
    __syncthreads();
    tmp[t] += u;
    __syncthreads();
  }
  if (t < nb) bsum[t] = tmp[t] - v;  // exclusive
}

__global__ __launch_bounds__(256) void scan_final(const int* __restrict__ deg,
                                                  const int* __restrict__ bsum,
                                                  int* __restrict__ rowptr,
                                                  int* __restrict__ cursor, int N, int E) {
  __shared__ int tmp[256];
  int t = threadIdx.x, b = blockIdx.x;
  int i0 = b * 1024 + t * 4;
  int v[4];
  int s = 0;
#pragma unroll
  for (int k = 0; k < 4; k++) {
    int i = i0 + k;
    v[k] = (i < N) ? deg[i] : 0;
    s += v[k];
  }
  tmp[t] = s;
  __syncthreads();
  for (int off = 1; off < 256; off <<= 1) {
    int u = (t >= off) ? tmp[t - off] : 0;
    __syncthreads();
    tmp[t] += u;
    __syncthreads();
  }
  int base = bsum[b] + (tmp[t] - s);
#pragma unroll
  for (int k = 0; k < 4; k++) {
    int i = i0 + k;
    if (i < N) {
      rowptr[i] = base;
      cursor[i] = base;
      base += v[k];
    }
  }
  if (b == 0 && t == 0) rowptr[N] = E;
}

// ---------------- scatter edges into CSR buckets ----------------

__global__ __launch_bounds__(256) void bucket_kernel(const int* __restrict__ src,
                                                     const int* __restrict__ dst,
                                                     int* __restrict__ cursor,
                                                     int2* __restrict__ pairs, int E) {
  int e = blockIdx.x * 256 + threadIdx.x;
  if (e < E) {
    int pos = atomicAdd(&cursor[dst[e]], 1);
    pairs[pos] = make_int2(src[e], e);
  }
}

// ---------------- prescale: xs = x * ns[row] ----------------

__global__ __launch_bounds__(256) void prescale_kernel(const float* __restrict__ x,
                                                       const float* __restrict__ ns,
                                                       float* __restrict__ xs, int Nn) {
  int i = blockIdx.x * 256 + threadIdx.x;  // one float4 per thread
  int total = Nn * (NFEAT / 4);
  if (i < total) {
    int row = i >> 5;
    float s = ns[row];
    float4 v = reinterpret_cast<const float4*>(x)[i];
    v.x *= s; v.y *= s; v.z *= s; v.w *= s;
    reinterpret_cast<float4*>(xs)[i] = v;
  }
}

// ---------------- gather aggregation ----------------
// agg[n,f] = sum_{e: dst[e]==n} feat[src[e],f] * [ns[src[e]] if SCALE_SRC]
//                                               * (mu[e] + sigma[e]*eps[e,f] if HAS_A)
// ONE 64-lane wave per node, split into two 32-lane halves; each half owns
// alternate edges and is unrolled x2 -> 4 independent load chains per wave.
// Halves combined at the end via shfl_xor(32).

template <bool HAS_A, bool NT, bool SCALE_SRC>
__global__ __launch_bounds__(256) void aggregate_kernel(const float* __restrict__ feat,
                                                        const int* __restrict__ rowptr,
                                                        const int2* __restrict__ pairs,
                                                        const float* __restrict__ ns,
                                                        const float2* __restrict__ musig,
                                                        const float* __restrict__ eps,
                                                        float* __restrict__ agg, int Nn) {
  int n = blockIdx.x * 4 + (threadIdx.x >> 6);
  if (n >= Nn) return;
  int lane = threadIdx.x & 63;
  int g = lane & 31;   // float4 index within the 128-feature row
  int eh = lane >> 5;  // half index: 0 or 1
  int beg = rowptr[n];
  int end = rowptr[n + 1];
  float4 acc = make_float4(0.f, 0.f, 0.f, 0.f);
  int j = beg + eh;
  // two edges per half in flight (global stride 4, within-half stride 2)
  for (; j + 2 < end; j += 4) {
    int2 p0 = pairs[j];
    int2 p1 = pairs[j + 2];
    float4 f0 = *(reinterpret_cast<const float4*>(feat + (size_t)p0.x * NFEAT) + g);
    float4 f1 = *(reinterpret_cast<const float4*>(feat + (size_t)p1.x * NFEAT) + g);
    if (SCALE_SRC) {
      float s0 = ns[p0.x];
      float s1 = ns[p1.x];
      f0.x *= s0; f0.y *= s0; f0.z *= s0; f0.w *= s0;
      f1.x *= s1; f1.y *= s1; f1.z *= s1; f1.w *= s1;
    }
    if (HAS_A) {
      float2 ms0 = musig[p0.y];
      float2 ms1 = musig[p1.y];
      const float4* e0p = reinterpret_cast<const float4*>(eps + (size_t)p0.y * NFEAT) + g;
      const float4* e1p = reinterpret_cast<const float4*>(eps + (size_t)p1.y * NFEAT) + g;
      float4 e0 = NT ? nt_load4(e0p) : *e0p;
      float4 e1 = NT ? nt_load4(e1p) : *e1p;
      acc.x = fmaf(f0.x, fmaf(ms0.y, e0.x, ms0.x), acc.x);
      acc.y = fmaf(f0.y, fmaf(ms0.y, e0.y, ms0.x), acc.y);
      acc.z = fmaf(f0.z, fmaf(ms0.y, e0.z, ms0.x), acc.z);
      acc.w = fmaf(f0.w, fmaf(ms0.y, e0.w, ms0.x), acc.w);
      acc.x = fmaf(f1.x, fmaf(ms1.y, e1.x, ms1.x), acc.x);
      acc.y = fmaf(f1.y, fmaf(ms1.y, e1.y, ms1.x), acc.y);
      acc.z = fmaf(f1.z, fmaf(ms1.y, e1.z, ms1.x), acc.z);
      acc.w = fmaf(f1.w, fmaf(ms1.y, e1.w, ms1.x), acc.w);
    } else {
      acc.x += f0.x + f1.x;
      acc.y += f0.y + f1.y;
      acc.z += f0.z + f1.z;
      acc.w += f0.w + f1.w;
    }
  }
  // remainder: at most one more edge for this half
  for (; j < end; j += 2) {
    int2 p0 = pairs[j];
    float4 f0 = *(reinterpret_cast<const float4*>(feat + (size_t)p0.x * NFEAT) + g);
    if (SCALE_SRC) {
      float s0 = ns[p0.x];
      f0.x *= s0; f0.y *= s0; f0.z *= s0; f0.w *= s0;
    }
    if (HAS_A) {
      float2 ms0 = musig[p0.y];
      const float4* e0p = reinterpret_cast<const float4*>(eps + (size_t)p0.y * NFEAT) + g;
      float4 e0 = NT ? nt_load4(e0p) : *e0p;
      acc.x = fmaf(f0.x, fmaf(ms0.y, e0.x, ms0.x), acc.x);
      acc.y = fmaf(f0.y, fmaf(ms0.y, e0.y, ms0.x), acc.y);
      acc.z = fmaf(f0.z, fmaf(ms0.y, e0.z, ms0.x), acc.z);
      acc.w = fmaf(f0.w, fmaf(ms0.y, e0.w, ms0.x), acc.w);
    } else {
      acc.x += f0.x; acc.y += f0.y; acc.z += f0.z; acc.w += f0.w;
    }
  }
  // combine the two halves (lane i <-> lane i^32 hold the same features)
  acc.x += __shfl_xor(acc.x, 32);
  acc.y += __shfl_xor(acc.y, 32);
  acc.z += __shfl_xor(acc.z, 32);
  acc.w += __shfl_xor(acc.w, 32);
  if (eh == 0)
    *reinterpret_cast<float4*>(agg + (size_t)n * NFEAT + g * 4) = acc;
}

// ---------------- dense layer: C = [ns_r *] relu((A*nd_r) @ W + b) ----------------

template <int NCOL, bool RELU, bool SCALE_NS>
__global__ __launch_bounds__(256) void matmul_kernel(const float* __restrict__ A,
                                                     const float* __restrict__ nd,
                                                     const float* __restrict__ ns,
                                                     const float* __restrict__ W,
                                                     const float* __restrict__ bias,
                                                     float* __restrict__ C, int nrows) {
  constexpr int OCG = NCOL / 4;
  constexpr int RG = 256 / OCG;
  constexpr int ROWS = RG * 4;
  __shared__ float Wl[128 * NCOL];
  for (int i = threadIdx.x; i < 128 * NCOL / 4; i += 256)
    reinterpret_cast<float4*>(Wl)[i] = reinterpret_cast<const float4*>(W)[i];
  __syncthreads();

  const int oc = threadIdx.x % OCG;
  const int rg = threadIdx.x / OCG;
  const int row0 = blockIdx.x * ROWS + rg * 4;

  const float* Arow[4];
#pragma unroll
  for (int i = 0; i < 4; i++) {
    int r = row0 + i;
    Arow[i] = A + (size_t)(r < nrows ? r : 0) * NFEAT;
  }
  float acc[4][4] = {};

#pragma unroll 2
  for (int k = 0; k < 128; k += 4) {
    float4 w0 = *reinterpret_cast<const float4*>(&Wl[(k + 0) * NCOL + oc * 4]);
    float4 w1 = *reinterpret_cast<const float4*>(&Wl[(k + 1) * NCOL + oc * 4]);
    float4 w2 = *reinterpret_cast<const float4*>(&Wl[(k + 2) * NCOL + oc * 4]);
    float4 w3 = *reinterpret_cast<const float4*>(&Wl[(k + 3) * NCOL + oc * 4]);
#pragma unroll
    for (int i = 0; i < 4; i++) {
      float4 a = *reinterpret_cast<const float4*>(Arow[i] + k);
      acc[i][0] = fmaf(a.x, w0.x, acc[i][0]);
      acc[i][1] = fmaf(a.x, w0.y, acc[i][1]);
      acc[i][2] = fmaf(a.x, w0.z, acc[i][2]);
      acc[i][3] = fmaf(a.x, w0.w, acc[i][3]);
      acc[i][0] = fmaf(a.y, w1.x, acc[i][0]);
      acc[i][1] = fmaf(a.y, w1.y, acc[i][1]);
      acc[i][2] = fmaf(a.y, w1.z, acc[i][2]);
      acc[i][3] = fmaf(a.y, w1.w, acc[i][3]);
      acc[i][0] = fmaf(a.z, w2.x, acc[i][0]);
      acc[i][1] = fmaf(a.z, w2.y, acc[i][1]);
      acc[i][2] = fmaf(a.z, w2.z, acc[i][2]);
      acc[i][3] = fmaf(a.z, w2.w, acc[i][3]);
      acc[i][0] = fmaf(a.w, w3.x, acc[i][0]);
      acc[i][1] = fmaf(a.w, w3.y, acc[i][1]);
      acc[i][2] = fmaf(a.w, w3.z, acc[i][2]);
      acc[i][3] = fmaf(a.w, w3.w, acc[i][3]);
    }
  }

  float4 b4 = *reinterpret_cast<const float4*>(bias + oc * 4);
#pragma unroll
  for (int i = 0; i < 4; i++) {
    int r = row0 + i;
    if (r < nrows) {
      float ndv = nd[r];
      float4 o;
      o.x = fmaf(acc[i][0], ndv, b4.x);
      o.y = fmaf(acc[i][1], ndv, b4.y);
      o.z = fmaf(acc[i][2], ndv, b4.z);
      o.w = fmaf(acc[i][3], ndv, b4.w);
      if (RELU) {
        o.x = fmaxf(o.x, 0.0f);
        o.y = fmaxf(o.y, 0.0f);
        o.z = fmaxf(o.z, 0.0f);
        o.w = fmaxf(o.w, 0.0f);
      }
      if (SCALE_NS) {
        float nsv = ns[r];
        o.x *= nsv; o.y *= nsv; o.z *= nsv; o.w *= nsv;
      }
      *reinterpret_cast<float4*>(C + (size_t)r * NCOL + oc * 4) = o;
    }
  }
}

// ---------------- per-node edge-MLP terms ----------------
// nt[n] = (dot(relu(z[n]),Wmu[0:128]), dot(relu(z[n]),Wmu[128:256]),
//          dot(relu(z[n]),Wls[0:128]), dot(relu(z[n]),Wls[128:256]))

__global__ __launch_bounds__(256) void node_terms_kernel(const float* __restrict__ z,
                                                         const float* __restrict__ W_mu,
                                                         const float* __restrict__ W_ls,
                                                         float4* __restrict__ nt, int Nn) {
  __shared__ float wl[512];
  {
    int i = threadIdx.x;
    wl[i] = W_mu[i];
    wl[256 + i] = W_ls[i];
  }
  __syncthreads();
  int n = blockIdx.x * 8 + (threadIdx.x >> 5);
  if (n >= Nn) return;
  int g = threadIdx.x & 31;
  float4 zv = *reinterpret_cast<const float4*>(z + (size_t)n * NFEAT + g * 4);
  zv.x = fmaxf(zv.x, 0.f); zv.y = fmaxf(zv.y, 0.f);
  zv.z = fmaxf(zv.z, 0.f); zv.w = fmaxf(zv.w, 0.f);
  float4 wma = *reinterpret_cast<const float4*>(&wl[g * 4]);
  float4 wmb = *reinterpret_cast<const float4*>(&wl[128 + g * 4]);
  float4 wla = *reinterpret_cast<const float4*>(&wl[256 + g * 4]);
  float4 wlb = *reinterpret_cast<const float4*>(&wl[384 + g * 4]);
  float pma = zv.x * wma.x + zv.y * wma.y + zv.z * wma.z + zv.w * wma.w;
  float pmb = zv.x * wmb.x + zv.y * wmb.y + zv.z * wmb.z + zv.w * wmb.w;
  float pla = zv.x * wla.x + zv.y * wla.y + zv.z * wla.z + zv.w * wla.w;
  float plb = zv.x * wlb.x + zv.y * wlb.y + zv.z * wlb.z + zv.w * wlb.w;
#pragma unroll
  for (int m = 16; m >= 1; m >>= 1) {
    pma += __shfl_xor(pma, m);
    pmb += __shfl_xor(pmb, m);
    pla += __shfl_xor(pla, m);
    plb += __shfl_xor(plb, m);
  }
  if (g == 0) nt[n] = make_float4(pma, pmb, pla, plb);
}

// ---------------- per-edge mu/sigma + NLL partials ----------------
// idx < E: positive edge (store musig, target 1); idx >= E: negative (target 0)

__global__ __launch_bounds__(256) void edge_kernel(const float4* __restrict__ nt,
                                                   const int* __restrict__ src,
                                                   const int* __restrict__ dst,
                                                   const int* __restrict__ neg_src,
                                                   const int* __restrict__ neg_dst,
                                                   const float* __restrict__ b_mu,
                                                   const float* __restrict__ b_ls,
                                                   float2* __restrict__ musig,
                                                   double2* __restrict__ partial, int E) {
  const float bmu = b_mu[0];
  const float bls = b_ls[0];
  double accP = 0.0, accN = 0.0;
  int stride = gridDim.x * 256;
  for (int idx = blockIdx.x * 256 + threadIdx.x; idx < 2 * E; idx += stride) {
    bool pos = idx < E;
    int e = pos ? idx : idx - E;
    int s = pos ? src[e] : neg_src[e];
    int d = pos ? dst[e] : neg_dst[e];
    float4 a = nt[s];
    float4 b = nt[d];
    float mu = a.x + b.y + bmu;
    float ls = a.z + b.w + bls;
    float sg = expf(ls);
    if (pos) musig[e] = make_float2(mu, sg);
    float dv = (pos ? 1.0f : 0.0f) - mu;
    float lp = -ls - 0.91893853320467274f - dv * dv / (2.0f * sg * sg);
    if (pos) accP += (double)lp; else accN += (double)lp;
  }
#pragma unroll
  for (int m = 1; m < 64; m <<= 1) {
    accP += __shfl_xor(accP, m);
    accN += __shfl_xor(accN, m);
  }
  __shared__ double2 wsum[4];
  if ((threadIdx.x & 63) == 0) wsum[threadIdx.x >> 6] = make_double2(accP, accN);
  __syncthreads();
  if (threadIdx.x == 0) {
    double sp = wsum[0].x + wsum[1].x + wsum[2].x + wsum[3].x;
    double sn = wsum[0].y + wsum[1].y + wsum[2].y + wsum[3].y;
    partial[blockIdx.x] = make_double2(sp, sn);
  }
}

__global__ __launch_bounds__(256) void finalize_kernel(const double2* __restrict__ partial,
                                                       int nb, float* __restrict__ out,
                                                       double invE) {
  double sp = 0.0, sn = 0.0;
  for (int i = threadIdx.x; i < nb; i += 256) {
    double2 pv = partial[i];
    sp += pv.x;
    sn += pv.y;
  }
#pragma unroll
  for (int m = 1; m < 64; m <<= 1) {
    sp += __shfl_xor(sp, m);
    sn += __shfl_xor(sn, m);
  }
  __shared__ double2 wsum[4];
  if ((threadIdx.x & 63) == 0) wsum[threadIdx.x >> 6] = make_double2(sp, sn);
  __syncthreads();
  if (threadIdx.x == 0) {
    double SP = wsum[0].x + wsum[1].x + wsum[2].x + wsum[3].x;
    double SN = wsum[0].y + wsum[1].y + wsum[2].y + wsum[3].y;
    out[0] = (float)(-(SP + SN) * invE);
  }
}

// ---------------- host-side orchestration ----------------

extern "C" void kernel_launch(void* const* d_in, const int* in_sizes, int n_in, void* d_out,
                              int out_size, void* d_ws, size_t ws_size, hipStream_t stream) {
  const float* x = (const float*)d_in[0];
  const int* src = (const int*)d_in[1];
  const int* dst = (const int*)d_in[2];
  const int* neg_src = (const int*)d_in[3];
  const int* neg_dst = (const int*)d_in[4];
  const float* eps_first = (const float*)d_in[5];
  const float* eps_rest = (const float*)d_in[6];
  const float* W_mu = (const float*)d_in[7];
  const float* b_mu = (const float*)d_in[8];
  const float* W_ls = (const float*)d_in[9];
  const float* b_ls = (const float*)d_in[10];
  const float* W_enc0 = (const float*)d_in[11];
  const float* b_enc0 = (const float*)d_in[12];
  const float* W_enc1 = (const float*)d_in[13];
  const float* b_enc1 = (const float*)d_in[14];
  const float* W_g0 = (const float*)d_in[15];
  const float* b_g0 = (const float*)d_in[16];
  const float* W_g1 = (const float*)d_in[17];
  const float* b_g1 = (const float*)d_in[18];
  const float* W_g2 = (const float*)d_in[19];
  const float* b_g2 = (const float*)d_in[20];

  const int N = in_sizes[0] / NFEAT;
  const int E = in_sizes[1];
  const int OUTF = 64;

  auto rnd = [](size_t b) { return (b + 255) & ~(size_t)255; };
  // fixed allocations (everything except xs):
  const size_t fixedBytes = rnd(EBLK * sizeof(double2)) + rnd((size_t)N * 4) * 2 +
                            rnd((size_t)E * 8) + rnd((size_t)(N + 1) * 4) +
                            rnd((size_t)N * 4) + rnd(256 * 4) + rnd((size_t)E * 8) +
                            rnd((size_t)N * 16) + 3 * rnd((size_t)N * NFEAT * 4);
  const bool useXs = fixedBytes + rnd((size_t)N * NFEAT * 4) <= ws_size;

  char* p = (char*)d_ws;
  auto alloc = [&](size_t bytes) -> char* {
    char* r = p;
    p += (bytes + 255) & ~(size_t)255;
    return r;
  };
  double2* partial = (double2*)alloc(EBLK * sizeof(double2));
  float* ns = (float*)alloc((size_t)N * 4);   // int degree then float ns, in place
  float* nd = (float*)alloc((size_t)N * 4);
  float2* musig = (float2*)alloc((size_t)E * 8);
  int* rowptr = (int*)alloc((size_t)(N + 1) * 4);
  int* cursor = (int*)alloc((size_t)N * 4);
  int* bsum = (int*)alloc(256 * 4);
  int2* pairs = (int2*)alloc((size_t)E * 8);
  float4* nt = (float4*)alloc((size_t)N * 16);
  float* agg = (float*)alloc((size_t)N * NFEAT * 4);
  float* bufH = (float*)alloc((size_t)N * NFEAT * 4);
  float* bufZ = (float*)alloc((size_t)N * NFEAT * 4);
  float* xs = useXs ? (float*)alloc((size_t)N * NFEAT * 4) : nullptr;

  float* outh = (float*)d_out;  // [N,64] then 1 float nll

  const int eBlocks = (E + 255) / 256;
  const int aggBlocks = (N + 3) / 4;       // 1 wave (64 lanes) per node, 4 nodes/block
  const int ntBlocks = (N + 7) / 8;
  const int mmBlocks128 = (N + 31) / 32;
  const int mmBlocks64 = (N + 63) / 64;
  const int nChunks = (N + 1023) / 1024;  // must be <= 256 (N=50k -> 49)

  (void)hipMemsetAsync(ns, 0, (size_t)N * 4, stream);
  (void)hipMemsetAsync(nd, 0, (size_t)N * 4, stream);

  // CSR build (dst buckets) + degree normalization
  hist_kernel<<<eBlocks, 256, 0, stream>>>(src, dst, (int*)ns, (int*)nd, E);
  scan_partial<<<nChunks, 256, 0, stream>>>((const int*)nd, bsum, N);
  scan_mid<<<1, 256, 0, stream>>>(bsum, nChunks);
  scan_final<<<nChunks, 256, 0, stream>>>((const int*)nd, bsum, rowptr, cursor, N, E);
  invsqrt_kernel<<<(N + 255) / 256, 256, 0, stream>>>(ns, N);
  invsqrt_kernel<<<(N + 255) / 256, 256, 0, stream>>>(nd, N);
  bucket_kernel<<<eBlocks, 256, 0, stream>>>(src, dst, cursor, pairs, E);

  const float* x0 = x;  // feat source for x-consuming aggregates
  if (useXs) {
    prescale_kernel<<<(N * 32 + 255) / 256, 256, 0, stream>>>(x, ns, xs, N);
    x0 = xs;
  }

  // encoder layer 0: bufH = ns * relu((agg(x*ns)*nd) @ W_enc0 + b)
  if (useXs)
    aggregate_kernel<false, false, false><<<aggBlocks, 256, 0, stream>>>(
        x0, rowptr, pairs, ns, nullptr, nullptr, agg, N);
  else
    aggregate_kernel<false, false, true><<<aggBlocks, 256, 0, stream>>>(
        x0, rowptr, pairs, ns, nullptr, nullptr, agg, N);
  matmul_kernel<128, true, true><<<mmBlocks128, 256, 0, stream>>>(agg, nd, ns, W_enc0,
                                                                  b_enc0, bufH, N);

  // encoder layer 1: bufZ = z (unscaled)
  aggregate_kernel<false, false, false><<<aggBlocks, 256, 0, stream>>>(
      bufH, rowptr, pairs, ns, nullptr, nullptr, agg, N);
  matmul_kernel<128, true, false><<<mmBlocks128, 256, 0, stream>>>(agg, nd, ns, W_enc1,
                                                                   b_enc1, bufZ, N);

  // per-node edge-MLP terms, then per-edge mu/sigma + nll partials
  node_terms_kernel<<<ntBlocks, 256, 0, stream>>>(bufZ, W_mu, W_ls, nt, N);
  edge_kernel<<<EBLK, 256, 0, stream>>>(nt, src, dst, neg_src, neg_dst, b_mu, b_ls, musig,
                                        partial, E);

  // stochastic layer 0 (eps_first, single-use -> nontemporal)
  if (useXs)
    aggregate_kernel<true, true, false><<<aggBlocks, 256, 0, stream>>>(
        x0, rowptr, pairs, ns, musig, eps_first, agg, N);
  else
    aggregate_kernel<true, true, true><<<aggBlocks, 256, 0, stream>>>(
        x0, rowptr, pairs, ns, musig, eps_first, agg, N);
  matmul_kernel<128, true, true><<<mmBlocks128, 256, 0, stream>>>(agg, nd, ns, W_g0, b_g0,
                                                                  bufH, N);

  // stochastic layer 1 (eps_rest, reused -> cached)
  aggregate_kernel<true, false, false><<<aggBlocks, 256, 0, stream>>>(
      bufH, rowptr, pairs, ns, musig, eps_rest, agg, N);
  matmul_kernel<128, true, true><<<mmBlocks128, 256, 0, stream>>>(agg, nd, ns, W_g1, b_g1,
                                                                  bufZ, N);

  // stochastic layer 2 (output, no relu, no scale)
  aggregate_kernel<true, false, false><<<aggBlocks, 256, 0, stream>>>(
      bufZ, rowptr, pairs, ns, musig, eps_rest, agg, N);
  matmul_kernel<64, false, false><<<mmBlocks64, 256, 0, stream>>>(agg, nd, ns, W_g2, b_g2,
                                                                  outh, N);

  // nll_reg scalar
  finalize_kernel<<<1, 256, 0, stream>>>(partial, EBLK, outh + (size_t)N * OUTF,
                                         1.0 / (double)E);
}